// Round 9
// baseline (6972.020 us; speedup 1.0000x reference)
//
#include <hip/hip_runtime.h>
#include <math.h>

#define B 8
#define T 4096
#define H 16
#define D 64
#define M 256

// SCALE = 2^-28 applied twice; irfft 1/T = 2^-12  ->  2^-68 (exact pow2)
#define TOTAL_SCALE 3.3881317890172014e-21f

// ---------------------------------------------------------------------------
// stable complex tanh, fp64 in, fp32 out
// ---------------------------------------------------------------------------
__device__ inline void ctanh_v4(double xr, double xi, float& tr, float& ti) {
    if (fabs(xr) > 20.0) {
        tr = (float)copysign(1.0, xr);
        ti = 0.0f;
    } else {
        double sh = sinh(2.0 * xr), ch = cosh(2.0 * xr);
        double sn = sin(2.0 * xi),  cs = cos(2.0 * xi);
        double den = ch + cs;
        tr = (float)(sh / den);
        ti = (float)(sn / den);
    }
}

// ---------------------------------------------------------------------------
// fp64 basis tables: c[t*M+m] = cos(2*pi*k_m*t/T), s[t*M+m] = sin(...)
// ---------------------------------------------------------------------------
__global__ void basis_v4(const int* __restrict__ idx,
                         double* __restrict__ c, double* __restrict__ s) {
    int gid = blockIdx.x * 256 + threadIdx.x;
    int t = gid >> 8;                    // M == 256
    int m = gid & (M - 1);
    int k = idx[m];
    int ph = (k * t) & (T - 1);          // exact: k*t < 2^23
    double th = (double)ph * (6.283185307179586476925287 / (double)T);
    c[gid] = cos(th);
    s[gid] = sin(th);
}

// ---------------------------------------------------------------------------
// forward DFT at selected modes, fp64 basis + fp64 accumulation, fp32 store
// (the complex64 cast — matches ref's rfft->c64 bits).
// grid (M/16, B*H), block 256
// ---------------------------------------------------------------------------
__launch_bounds__(256)
__global__ void dft_v4(const float* __restrict__ x,
                       const double* __restrict__ bc, const double* __restrict__ bs,
                       float* __restrict__ Xre, float* __restrict__ Xim) {
    __shared__ float  xch[64][65];       // [t_local][d]
    __shared__ double bcc[64][17];       // [t_local][m_local]
    __shared__ double bss[64][17];
    int mt = blockIdx.x;                 // modes mt*16 .. +15
    int bh = blockIdx.y;                 // 0..127
    int b = bh >> 4, h = bh & 15;
    int tid = threadIdx.x;
    int d = tid & 63, mg = tid >> 6;     // mg 0..3 -> 4 modes each
    const float* xb = x + (size_t)b * T * H * D + (size_t)h * D;

    double aR[4] = {0, 0, 0, 0}, aI[4] = {0, 0, 0, 0};

    for (int t0 = 0; t0 < T; t0 += 64) {
        __syncthreads();
        #pragma unroll
        for (int i = 0; i < 16; i++) {   // 4096 = 64*64
            int lin = i * 256 + tid;
            int tl = lin >> 6, dd = lin & 63;
            xch[tl][dd] = xb[(size_t)(t0 + tl) * (H * D) + dd];
        }
        #pragma unroll
        for (int i = 0; i < 4; i++) {    // 1024 = 64*16
            int lin = i * 256 + tid;
            int tl = lin >> 4, ml = lin & 15;
            bcc[tl][ml] = bc[(size_t)(t0 + tl) * M + mt * 16 + ml];
            bss[tl][ml] = bs[(size_t)(t0 + tl) * M + mt * 16 + ml];
        }
        __syncthreads();
        for (int tl = 0; tl < 64; tl++) {
            double xv = (double)xch[tl][d];
            #pragma unroll
            for (int j = 0; j < 4; j++) {
                int ml = mg * 4 + j;
                aR[j] = fma(xv, bcc[tl][ml], aR[j]);
                aI[j] = fma(-xv, bss[tl][ml], aI[j]);
            }
        }
    }
    size_t base = ((size_t)bh * D + d) * M + mt * 16 + mg * 4;
    #pragma unroll
    for (int j = 0; j < 4; j++) {
        Xre[base + j] = (float)aR[j];    // the complex64 cast
        Xim[base + j] = (float)aI[j];
    }
}

// ---------------------------------------------------------------------------
// fused attn+pv. Pre-tanh dot: fp32, d ascending, FUSED fmaf chains
// (fresh rounding realization vs round-6's non-fused variant).
//   attn[x,y] = ctanh64( fp32 fma-dot )
//   xqkv[d,x] = sum_y attn[x,y]*Xv[d,y]          (fp32, linear path)
// grid (M/32, B*H), block 256.
// ---------------------------------------------------------------------------
__launch_bounds__(256)
__global__ void attnpv_v4(const float* __restrict__ Xq_re, const float* __restrict__ Xq_im,
                          const float* __restrict__ Xk_re, const float* __restrict__ Xk_im,
                          const float* __restrict__ Xv_re, const float* __restrict__ Xv_im,
                          float* __restrict__ xq_re, float* __restrict__ xq_im) {
    __shared__ float qr[64][33], qi[64][33];   // [d][x_local]
    __shared__ float kr[64][33], ki[64][33];   // [d][y_local]
    __shared__ float vr[64][33], vi[64][33];
    __shared__ float atr[32][33], ati[32][33]; // [x_local][y_local]
    int x0 = blockIdx.x * 32;
    int bh = blockIdx.y;
    int tid = threadIdx.x;
    size_t base = (size_t)bh * D * M;

    // load Q tile once: 64d x 32x
    #pragma unroll
    for (int i = 0; i < 8; i++) {
        int lin = i * 256 + tid;
        int dd = lin >> 5, xl = lin & 31;
        qr[dd][xl] = Xq_re[base + (size_t)dd * M + x0 + xl];
        qi[dd][xl] = Xq_im[base + (size_t)dd * M + x0 + xl];
    }

    int xa = tid & 31, yga = tid >> 5;   // attn phase: (x, 4 y's)
    int dp = tid & 63, xgp = tid >> 6;   // pv phase:   (d, 8 x's)
    float pr[8] = {0}, pi[8] = {0};

    for (int y0 = 0; y0 < M; y0 += 32) {
        __syncthreads();                 // guards Q load (iter0) + k/v/at reuse
        #pragma unroll
        for (int i = 0; i < 8; i++) {
            int lin = i * 256 + tid;
            int dd = lin >> 5, yl = lin & 31;
            size_t g = base + (size_t)dd * M + y0 + yl;
            kr[dd][yl] = Xk_re[g];
            ki[dd][yl] = Xk_im[g];
            vr[dd][yl] = Xv_re[g];
            vi[dd][yl] = Xv_im[g];
        }
        __syncthreads();

        // ---- fp32 serial-d dots, FMA-fused accumulation
        float ar[4] = {0, 0, 0, 0}, ai[4] = {0, 0, 0, 0};
        for (int dd = 0; dd < 64; dd++) {
            float qre = qr[dd][xa], qim = qi[dd][xa];
            #pragma unroll
            for (int jj = 0; jj < 4; jj++) {
                int yl = yga * 4 + jj;
                float kre = kr[dd][yl], kim = ki[dd][yl];
                ar[jj] = fmaf(qre, kre, fmaf(-qim, kim, ar[jj]));
                ai[jj] = fmaf(qre, kim, fmaf(qim, kre, ai[jj]));
            }
        }
        #pragma unroll
        for (int jj = 0; jj < 4; jj++) {
            float tr, ti;
            ctanh_v4((double)ar[jj], (double)ai[jj], tr, ti);
            atr[xa][yga * 4 + jj] = tr;
            ati[xa][yga * 4 + jj] = ti;
        }
        __syncthreads();

        // ---- pv accumulate: xqkv[dp, x] += attn[x,y]*Xv[dp,y]
        for (int yl = 0; yl < 32; yl++) {
            float vre = vr[dp][yl], vim = vi[dp][yl];
            #pragma unroll
            for (int j = 0; j < 8; j++) {
                int xl = xgp * 8 + j;
                float are = atr[xl][yl], aim = ati[xl][yl];
                pr[j] += are * vre - aim * vim;
                pi[j] += are * vim + aim * vre;
            }
        }
    }
    size_t ob = base + (size_t)dp * M + x0 + xgp * 8;
    #pragma unroll
    for (int j = 0; j < 8; j++) {
        xq_re[ob + j] = pr[j];
        xq_im[ob + j] = pi[j];
    }
}

// ---------------------------------------------------------------------------
// xw[bh,o,m] = sum_d xqkv[bh,d,m] * w[h,d,o,m]   (fp64 accumulation)
// grid (M/32, B*H), block 256
// ---------------------------------------------------------------------------
__launch_bounds__(256)
__global__ void wmul_v4(const float* __restrict__ xqkv_re, const float* __restrict__ xqkv_im,
                        const float* __restrict__ w_re, const float* __restrict__ w_im,
                        float* __restrict__ xw_re, float* __restrict__ xw_im) {
    __shared__ float xr[64][33], xi[64][33];   // [d][x_local]
    int x0 = blockIdx.x * 32;
    int bh = blockIdx.y;
    int h = bh & 15;
    int tid = threadIdx.x;
    int xl = tid & 31, og = tid >> 5;          // og 0..7 -> o = og*8..+7
    size_t base = (size_t)bh * D * M;

    #pragma unroll
    for (int i = 0; i < 8; i++) {
        int lin = i * 256 + tid;
        int dd = lin >> 5, xx = lin & 31;
        xr[dd][xx] = xqkv_re[base + (size_t)dd * M + x0 + xx];
        xi[dd][xx] = xqkv_im[base + (size_t)dd * M + x0 + xx];
    }
    __syncthreads();

    double aR[8] = {0}, aI[8] = {0};
    const float* wrb = w_re + (size_t)h * D * D * M + x0 + xl;
    const float* wib = w_im + (size_t)h * D * D * M + x0 + xl;
    for (int dd = 0; dd < 64; dd++) {
        double xre = (double)xr[dd][xl], xim = (double)xi[dd][xl];
        #pragma unroll
        for (int j = 0; j < 8; j++) {
            int o = og * 8 + j;
            double wre = (double)wrb[((size_t)dd * D + o) * M];
            double wim = (double)wib[((size_t)dd * D + o) * M];
            aR[j] = fma(xre, wre, aR[j]);
            aR[j] = fma(-xim, wim, aR[j]);
            aI[j] = fma(xre, wim, aI[j]);
            aI[j] = fma(xim, wre, aI[j]);
        }
    }
    size_t ob = base + (size_t)(og * 8) * M + x0 + xl;
    #pragma unroll
    for (int j = 0; j < 8; j++) {
        xw_re[ob + (size_t)j * M] = (float)aR[j];
        xw_im[ob + (size_t)j * M] = (float)aI[j];
    }
}

// ---------------------------------------------------------------------------
// sparse iDFT + conj-symmetry weights + transpose to (b,t,h,o):
//   out[b,t,h,o] = sum_m wsc_m * (xw_re*cos - xw_im*sin),
//   wsc = (k==0?1:2) * 2^-68
// grid (T/64, B*H), block 256
// ---------------------------------------------------------------------------
__launch_bounds__(256)
__global__ void idft_v4(const float* __restrict__ xw_re, const float* __restrict__ xw_im,
                        const double* __restrict__ bc, const double* __restrict__ bs,
                        const int* __restrict__ idxq, float* __restrict__ out) {
    __shared__ float wr[64][65], wi[64][65];   // [o][m_local]
    __shared__ float cc[64][65], ss[64][65];   // [t_local][m_local]
    int t0 = blockIdx.x * 64;
    int bh = blockIdx.y;
    int b = bh >> 4, h = bh & 15;
    int tid = threadIdx.x;
    int ol = tid & 63, tg = tid >> 6;          // tg 0..3 -> 16 t's each
    size_t base = (size_t)bh * D * M;
    float acc[16] = {0};

    for (int m0 = 0; m0 < M; m0 += 64) {
        __syncthreads();
        #pragma unroll
        for (int i = 0; i < 16; i++) {
            int lin = i * 256 + tid;
            int oo = lin >> 6, ml = lin & 63;
            int k = idxq[m0 + ml];
            float wsc = (k == 0 ? 1.0f : 2.0f) * TOTAL_SCALE;
            wr[oo][ml] = xw_re[base + (size_t)oo * M + m0 + ml] * wsc;
            wi[oo][ml] = xw_im[base + (size_t)oo * M + m0 + ml] * wsc;
        }
        #pragma unroll
        for (int i = 0; i < 16; i++) {
            int lin = i * 256 + tid;
            int tl = lin >> 6, ml = lin & 63;
            cc[tl][ml] = (float)bc[(size_t)(t0 + tl) * M + m0 + ml];
            ss[tl][ml] = (float)bs[(size_t)(t0 + tl) * M + m0 + ml];
        }
        __syncthreads();

        for (int ml = 0; ml < 64; ml++) {
            float xre = wr[ol][ml], xim = wi[ol][ml];
            #pragma unroll
            for (int j = 0; j < 16; j++) {
                int tl = tg * 16 + j;
                acc[j] = fmaf(cc[tl][ml], xre, acc[j]);
                acc[j] = fmaf(-ss[tl][ml], xim, acc[j]);
            }
        }
    }
    #pragma unroll
    for (int j = 0; j < 16; j++) {
        int t = t0 + tg * 16 + j;
        out[(((size_t)b * T + t) * H + h) * D + ol] = acc[j];
    }
}

// ---------------------------------------------------------------------------
extern "C" void kernel_launch(void* const* d_in, const int* in_sizes, int n_in,
                              void* d_out, int out_size, void* d_ws, size_t ws_size,
                              hipStream_t stream) {
    const float* q    = (const float*)d_in[0];
    const float* k    = (const float*)d_in[1];
    const float* v    = (const float*)d_in[2];
    const float* w_re = (const float*)d_in[3];
    const float* w_im = (const float*)d_in[4];
    const int* idx_q  = (const int*)d_in[5];
    const int* idx_kv = (const int*)d_in[6];
    float* out = (float*)d_out;

    const size_t TM  = (size_t)T * M;          // 1,048,576
    const size_t XSZ = (size_t)B * H * D * M;  // 2,097,152

    // ---- ws: 4*TM doubles (32 MiB basis) + 6*XSZ floats (48 MiB) = 80 MiB --
    double* bq_c  = (double*)d_ws;             // fp64 basis (index_q)
    double* bq_s  = bq_c + TM;
    double* bkv_c = bq_s + TM;                 // fp64 basis (index_kv)
    double* bkv_s = bkv_c + TM;
    float*  Xv_re = (float*)(bkv_s + TM);
    float*  Xv_im = Xv_re + XSZ;
    float*  xqkv_re = Xv_im + XSZ;
    float*  xqkv_im = xqkv_re + XSZ;
    float*  xw_re = xqkv_im + XSZ;
    float*  xw_im = xw_re + XSZ;

    // ---- d_out scratch: Xq/Xk fp32 (33.5 MB at the tail); consumed by
    //      attnpv_v4 before idft_v4 rewrites every element of d_out. ------
    float* Xq_re32 = out + (size_t)out_size - 4 * XSZ;
    float* Xq_im32 = Xq_re32 + XSZ;
    float* Xk_re32 = Xq_im32 + XSZ;
    float* Xk_im32 = Xk_re32 + XSZ;

    basis_v4<<<TM / 256, 256, 0, stream>>>(idx_q, bq_c, bq_s);
    basis_v4<<<TM / 256, 256, 0, stream>>>(idx_kv, bkv_c, bkv_s);

    dft_v4<<<dim3(M / 16, B * H), 256, 0, stream>>>(q, bq_c, bq_s, Xq_re32, Xq_im32);
    dft_v4<<<dim3(M / 16, B * H), 256, 0, stream>>>(k, bkv_c, bkv_s, Xk_re32, Xk_im32);
    dft_v4<<<dim3(M / 16, B * H), 256, 0, stream>>>(v, bkv_c, bkv_s, Xv_re, Xv_im);

    attnpv_v4<<<dim3(M / 32, B * H), 256, 0, stream>>>(
        Xq_re32, Xq_im32, Xk_re32, Xk_im32, Xv_re, Xv_im, xqkv_re, xqkv_im);

    wmul_v4<<<dim3(M / 32, B * H), 256, 0, stream>>>(
        xqkv_re, xqkv_im, w_re, w_im, xw_re, xw_im);

    idft_v4<<<dim3(T / 64, B * H), 256, 0, stream>>>(
        xw_re, xw_im, bq_c, bq_s, idx_q, out);
}

// Round 10
// 4169.063 us; speedup vs baseline: 1.6723x; 1.6723x over previous
//
#include <hip/hip_runtime.h>
#include <math.h>

#define B 8
#define T 4096
#define H 16
#define D 64
#define M 256
#define TT 32   // DFT t-tile

// SCALE = 2^-28 applied twice; irfft 1/T = 2^-12  ->  2^-68 (exact pow2)
#define TOTAL_SCALE 3.3881317890172014e-21f

// ---------------------------------------------------------------------------
// stable complex tanh, fp64 in, fp32 out
// ---------------------------------------------------------------------------
__device__ inline void ctanh_v4(double xr, double xi, float& tr, float& ti) {
    if (fabs(xr) > 20.0) {
        tr = (float)copysign(1.0, xr);
        ti = 0.0f;
    } else {
        double sh = sinh(2.0 * xr), ch = cosh(2.0 * xr);
        double sn = sin(2.0 * xi),  cs = cos(2.0 * xi);
        double den = ch + cs;
        tr = (float)(sh / den);
        ti = (float)(sn / den);
    }
}

// ---------------------------------------------------------------------------
// fp64 basis tables: c[t*M+m] = cos(2*pi*k_m*t/T), s[t*M+m] = sin(...)
// ---------------------------------------------------------------------------
__global__ void basis_v4(const int* __restrict__ idx,
                         double* __restrict__ c, double* __restrict__ s) {
    int gid = blockIdx.x * 256 + threadIdx.x;
    int t = gid >> 8;                    // M == 256
    int m = gid & (M - 1);
    int k = idx[m];
    int ph = (k * t) & (T - 1);          // exact: k*t < 2^23
    double th = (double)ph * (6.283185307179586476925287 / (double)T);
    c[gid] = cos(th);
    s[gid] = sin(th);
}

// ---------------------------------------------------------------------------
// forward DFT at selected modes — register-tiled fp64 GEMM.
// Block: 64 modes x 64 d, full T loop in tiles of TT=32.
// Thread (dg=tid&15, mg=tid>>4): 4 d x 4 m tile, 32 fp64 FMA per tl vs
// 5 vector LDS reads (1 float4 + 4 double2).
// Accumulation order per output identical to dft_v4 (t ascending, one fma
// per t) -> bit-identical X -> bit-identical final output.
// grid (M/64, B*H), block 256
// ---------------------------------------------------------------------------
__launch_bounds__(256)
__global__ void dft_v5(const float* __restrict__ x,
                       const double* __restrict__ bc, const double* __restrict__ bs,
                       float* __restrict__ Xre, float* __restrict__ Xim) {
    __shared__ float  xs[TT][68];        // [tl][d], stride 272B (16B-aligned)
    __shared__ double cs_[TT][66];       // [tl][m_local], stride 528B
    __shared__ double sn_[TT][66];
    int m0 = blockIdx.x * 64;
    int bh = blockIdx.y;
    int b = bh >> 4, h = bh & 15;
    int tid = threadIdx.x;
    int dg = tid & 15, mg = tid >> 4;    // 4 d's = dg*4.., 4 m's = mg*4..
    const float* xb = x + (size_t)b * T * H * D + (size_t)h * D;

    double aR[4][4] = {}, aI[4][4] = {};

    for (int t0 = 0; t0 < T; t0 += TT) {
        __syncthreads();
        #pragma unroll
        for (int i = 0; i < 2; i++) {    // x: 512 float4
            int lin = i * 256 + tid;
            int tl = lin >> 4, c4 = lin & 15;
            *(float4*)&xs[tl][c4 * 4] =
                *(const float4*)&xb[(size_t)(t0 + tl) * (H * D) + c4 * 4];
        }
        #pragma unroll
        for (int i = 0; i < 4; i++) {    // basis: 1024 double2 each
            int lin = i * 256 + tid;
            int tl = lin >> 5, c2 = lin & 31;
            *(double2*)&cs_[tl][c2 * 2] =
                *(const double2*)&bc[(size_t)(t0 + tl) * M + m0 + c2 * 2];
            *(double2*)&sn_[tl][c2 * 2] =
                *(const double2*)&bs[(size_t)(t0 + tl) * M + m0 + c2 * 2];
        }
        __syncthreads();

        for (int tl = 0; tl < TT; tl++) {
            float4 xf = *(float4*)&xs[tl][dg * 4];
            double xv[4] = {(double)xf.x, (double)xf.y, (double)xf.z, (double)xf.w};
            double2 cA = *(double2*)&cs_[tl][mg * 4];
            double2 cB = *(double2*)&cs_[tl][mg * 4 + 2];
            double2 sA = *(double2*)&sn_[tl][mg * 4];
            double2 sB = *(double2*)&sn_[tl][mg * 4 + 2];
            double cj[4]  = {cA.x, cA.y, cB.x, cB.y};
            double nsj[4] = {-sA.x, -sA.y, -sB.x, -sB.y};
            #pragma unroll
            for (int i2 = 0; i2 < 4; i2++) {
                #pragma unroll
                for (int j = 0; j < 4; j++) {
                    aR[i2][j] = fma(xv[i2], cj[j],  aR[i2][j]);
                    aI[i2][j] = fma(xv[i2], nsj[j], aI[i2][j]);
                }
            }
        }
    }

    #pragma unroll
    for (int i2 = 0; i2 < 4; i2++) {
        int d = dg * 4 + i2;
        size_t base = ((size_t)bh * D + d) * M + m0 + mg * 4;
        #pragma unroll
        for (int j = 0; j < 4; j++) {
            Xre[base + j] = (float)aR[i2][j];   // the complex64 cast
            Xim[base + j] = (float)aI[i2][j];
        }
    }
}

// ---------------------------------------------------------------------------
// fused attn+pv. Pre-tanh dot: fp32, d ascending, FUSED fmaf chains.
//   attn[x,y] = ctanh64( fp32 fma-dot )
//   xqkv[d,x] = sum_y attn[x,y]*Xv[d,y]          (fp32, linear path)
// grid (M/32, B*H), block 256.
// ---------------------------------------------------------------------------
__launch_bounds__(256)
__global__ void attnpv_v4(const float* __restrict__ Xq_re, const float* __restrict__ Xq_im,
                          const float* __restrict__ Xk_re, const float* __restrict__ Xk_im,
                          const float* __restrict__ Xv_re, const float* __restrict__ Xv_im,
                          float* __restrict__ xq_re, float* __restrict__ xq_im) {
    __shared__ float qr[64][33], qi[64][33];   // [d][x_local]
    __shared__ float kr[64][33], ki[64][33];   // [d][y_local]
    __shared__ float vr[64][33], vi[64][33];
    __shared__ float atr[32][33], ati[32][33]; // [x_local][y_local]
    int x0 = blockIdx.x * 32;
    int bh = blockIdx.y;
    int tid = threadIdx.x;
    size_t base = (size_t)bh * D * M;

    // load Q tile once: 64d x 32x
    #pragma unroll
    for (int i = 0; i < 8; i++) {
        int lin = i * 256 + tid;
        int dd = lin >> 5, xl = lin & 31;
        qr[dd][xl] = Xq_re[base + (size_t)dd * M + x0 + xl];
        qi[dd][xl] = Xq_im[base + (size_t)dd * M + x0 + xl];
    }

    int xa = tid & 31, yga = tid >> 5;   // attn phase: (x, 4 y's)
    int dp = tid & 63, xgp = tid >> 6;   // pv phase:   (d, 8 x's)
    float pr[8] = {0}, pi[8] = {0};

    for (int y0 = 0; y0 < M; y0 += 32) {
        __syncthreads();                 // guards Q load (iter0) + k/v/at reuse
        #pragma unroll
        for (int i = 0; i < 8; i++) {
            int lin = i * 256 + tid;
            int dd = lin >> 5, yl = lin & 31;
            size_t g = base + (size_t)dd * M + y0 + yl;
            kr[dd][yl] = Xk_re[g];
            ki[dd][yl] = Xk_im[g];
            vr[dd][yl] = Xv_re[g];
            vi[dd][yl] = Xv_im[g];
        }
        __syncthreads();

        // ---- fp32 serial-d dots, FMA-fused accumulation
        float ar[4] = {0, 0, 0, 0}, ai[4] = {0, 0, 0, 0};
        for (int dd = 0; dd < 64; dd++) {
            float qre = qr[dd][xa], qim = qi[dd][xa];
            #pragma unroll
            for (int jj = 0; jj < 4; jj++) {
                int yl = yga * 4 + jj;
                float kre = kr[dd][yl], kim = ki[dd][yl];
                ar[jj] = fmaf(qre, kre, fmaf(-qim, kim, ar[jj]));
                ai[jj] = fmaf(qre, kim, fmaf(qim, kre, ai[jj]));
            }
        }
        #pragma unroll
        for (int jj = 0; jj < 4; jj++) {
            float tr, ti;
            ctanh_v4((double)ar[jj], (double)ai[jj], tr, ti);
            atr[xa][yga * 4 + jj] = tr;
            ati[xa][yga * 4 + jj] = ti;
        }
        __syncthreads();

        // ---- pv accumulate: xqkv[dp, x] += attn[x,y]*Xv[dp,y]
        for (int yl = 0; yl < 32; yl++) {
            float vre = vr[dp][yl], vim = vi[dp][yl];
            #pragma unroll
            for (int j = 0; j < 8; j++) {
                int xl = xgp * 8 + j;
                float are = atr[xl][yl], aim = ati[xl][yl];
                pr[j] += are * vre - aim * vim;
                pi[j] += are * vim + aim * vre;
            }
        }
    }
    size_t ob = base + (size_t)dp * M + x0 + xgp * 8;
    #pragma unroll
    for (int j = 0; j < 8; j++) {
        xq_re[ob + j] = pr[j];
        xq_im[ob + j] = pi[j];
    }
}

// ---------------------------------------------------------------------------
// xw[bh,o,m] = sum_d xqkv[bh,d,m] * w[h,d,o,m]   (fp64 accumulation)
// grid (M/32, B*H), block 256
// ---------------------------------------------------------------------------
__launch_bounds__(256)
__global__ void wmul_v4(const float* __restrict__ xqkv_re, const float* __restrict__ xqkv_im,
                        const float* __restrict__ w_re, const float* __restrict__ w_im,
                        float* __restrict__ xw_re, float* __restrict__ xw_im) {
    __shared__ float xr[64][33], xi[64][33];   // [d][x_local]
    int x0 = blockIdx.x * 32;
    int bh = blockIdx.y;
    int h = bh & 15;
    int tid = threadIdx.x;
    int xl = tid & 31, og = tid >> 5;          // og 0..7 -> o = og*8..+7
    size_t base = (size_t)bh * D * M;

    #pragma unroll
    for (int i = 0; i < 8; i++) {
        int lin = i * 256 + tid;
        int dd = lin >> 5, xx = lin & 31;
        xr[dd][xx] = xqkv_re[base + (size_t)dd * M + x0 + xx];
        xi[dd][xx] = xqkv_im[base + (size_t)dd * M + x0 + xx];
    }
    __syncthreads();

    double aR[8] = {0}, aI[8] = {0};
    const float* wrb = w_re + (size_t)h * D * D * M + x0 + xl;
    const float* wib = w_im + (size_t)h * D * D * M + x0 + xl;
    for (int dd = 0; dd < 64; dd++) {
        double xre = (double)xr[dd][xl], xim = (double)xi[dd][xl];
        #pragma unroll
        for (int j = 0; j < 8; j++) {
            int o = og * 8 + j;
            double wre = (double)wrb[((size_t)dd * D + o) * M];
            double wim = (double)wib[((size_t)dd * D + o) * M];
            aR[j] = fma(xre, wre, aR[j]);
            aR[j] = fma(-xim, wim, aR[j]);
            aI[j] = fma(xre, wim, aI[j]);
            aI[j] = fma(xim, wre, aI[j]);
        }
    }
    size_t ob = base + (size_t)(og * 8) * M + x0 + xl;
    #pragma unroll
    for (int j = 0; j < 8; j++) {
        xw_re[ob + (size_t)j * M] = (float)aR[j];
        xw_im[ob + (size_t)j * M] = (float)aI[j];
    }
}

// ---------------------------------------------------------------------------
// sparse iDFT + conj-symmetry weights + transpose to (b,t,h,o):
//   out[b,t,h,o] = sum_m wsc_m * (xw_re*cos - xw_im*sin),
//   wsc = (k==0?1:2) * 2^-68
// grid (T/64, B*H), block 256
// ---------------------------------------------------------------------------
__launch_bounds__(256)
__global__ void idft_v4(const float* __restrict__ xw_re, const float* __restrict__ xw_im,
                        const double* __restrict__ bc, const double* __restrict__ bs,
                        const int* __restrict__ idxq, float* __restrict__ out) {
    __shared__ float wr[64][65], wi[64][65];   // [o][m_local]
    __shared__ float cc[64][65], ss[64][65];   // [t_local][m_local]
    int t0 = blockIdx.x * 64;
    int bh = blockIdx.y;
    int b = bh >> 4, h = bh & 15;
    int tid = threadIdx.x;
    int ol = tid & 63, tg = tid >> 6;          // tg 0..3 -> 16 t's each
    size_t base = (size_t)bh * D * M;
    float acc[16] = {0};

    for (int m0 = 0; m0 < M; m0 += 64) {
        __syncthreads();
        #pragma unroll
        for (int i = 0; i < 16; i++) {
            int lin = i * 256 + tid;
            int oo = lin >> 6, ml = lin & 63;
            int k = idxq[m0 + ml];
            float wsc = (k == 0 ? 1.0f : 2.0f) * TOTAL_SCALE;
            wr[oo][ml] = xw_re[base + (size_t)oo * M + m0 + ml] * wsc;
            wi[oo][ml] = xw_im[base + (size_t)oo * M + m0 + ml] * wsc;
        }
        #pragma unroll
        for (int i = 0; i < 16; i++) {
            int lin = i * 256 + tid;
            int tl = lin >> 6, ml = lin & 63;
            cc[tl][ml] = (float)bc[(size_t)(t0 + tl) * M + m0 + ml];
            ss[tl][ml] = (float)bs[(size_t)(t0 + tl) * M + m0 + ml];
        }
        __syncthreads();

        for (int ml = 0; ml < 64; ml++) {
            float xre = wr[ol][ml], xim = wi[ol][ml];
            #pragma unroll
            for (int j = 0; j < 16; j++) {
                int tl = tg * 16 + j;
                acc[j] = fmaf(cc[tl][ml], xre, acc[j]);
                acc[j] = fmaf(-ss[tl][ml], xim, acc[j]);
            }
        }
    }
    #pragma unroll
    for (int j = 0; j < 16; j++) {
        int t = t0 + tg * 16 + j;
        out[(((size_t)b * T + t) * H + h) * D + ol] = acc[j];
    }
}

// ---------------------------------------------------------------------------
extern "C" void kernel_launch(void* const* d_in, const int* in_sizes, int n_in,
                              void* d_out, int out_size, void* d_ws, size_t ws_size,
                              hipStream_t stream) {
    const float* q    = (const float*)d_in[0];
    const float* k    = (const float*)d_in[1];
    const float* v    = (const float*)d_in[2];
    const float* w_re = (const float*)d_in[3];
    const float* w_im = (const float*)d_in[4];
    const int* idx_q  = (const int*)d_in[5];
    const int* idx_kv = (const int*)d_in[6];
    float* out = (float*)d_out;

    const size_t TM  = (size_t)T * M;          // 1,048,576
    const size_t XSZ = (size_t)B * H * D * M;  // 2,097,152

    // ---- ws: 4*TM doubles (32 MiB basis) + 6*XSZ floats (48 MiB) = 80 MiB --
    double* bq_c  = (double*)d_ws;             // fp64 basis (index_q)
    double* bq_s  = bq_c + TM;
    double* bkv_c = bq_s + TM;                 // fp64 basis (index_kv)
    double* bkv_s = bkv_c + TM;
    float*  Xv_re = (float*)(bkv_s + TM);
    float*  Xv_im = Xv_re + XSZ;
    float*  xqkv_re = Xv_im + XSZ;
    float*  xqkv_im = xqkv_re + XSZ;
    float*  xw_re = xqkv_im + XSZ;
    float*  xw_im = xw_re + XSZ;

    // ---- d_out scratch: Xq/Xk fp32 (33.5 MB at the tail); consumed by
    //      attnpv_v4 before idft_v4 rewrites every element of d_out. ------
    float* Xq_re32 = out + (size_t)out_size - 4 * XSZ;
    float* Xq_im32 = Xq_re32 + XSZ;
    float* Xk_re32 = Xq_im32 + XSZ;
    float* Xk_im32 = Xk_re32 + XSZ;

    basis_v4<<<TM / 256, 256, 0, stream>>>(idx_q, bq_c, bq_s);
    basis_v4<<<TM / 256, 256, 0, stream>>>(idx_kv, bkv_c, bkv_s);

    dft_v5<<<dim3(M / 64, B * H), 256, 0, stream>>>(q, bq_c, bq_s, Xq_re32, Xq_im32);
    dft_v5<<<dim3(M / 64, B * H), 256, 0, stream>>>(k, bkv_c, bkv_s, Xk_re32, Xk_im32);
    dft_v5<<<dim3(M / 64, B * H), 256, 0, stream>>>(v, bkv_c, bkv_s, Xv_re, Xv_im);

    attnpv_v4<<<dim3(M / 32, B * H), 256, 0, stream>>>(
        Xq_re32, Xq_im32, Xk_re32, Xk_im32, Xv_re, Xv_im, xqkv_re, xqkv_im);

    wmul_v4<<<dim3(M / 32, B * H), 256, 0, stream>>>(
        xqkv_re, xqkv_im, w_re, w_im, xw_re, xw_im);

    idft_v4<<<dim3(T / 64, B * H), 256, 0, stream>>>(
        xw_re, xw_im, bq_c, bq_s, idx_q, out);
}

// Round 11
// 3584.320 us; speedup vs baseline: 1.9451x; 1.1631x over previous
//
#include <hip/hip_runtime.h>
#include <math.h>

#define B 8
#define T 4096
#define H 16
#define D 64
#define M 256
#define TT 32   // DFT t-tile

// SCALE = 2^-28 applied twice; irfft 1/T = 2^-12  ->  2^-68 (exact pow2)
#define TOTAL_SCALE 3.3881317890172014e-21f

// ---------------------------------------------------------------------------
// stable complex tanh, fp64 in, fp32 out
// ---------------------------------------------------------------------------
__device__ inline void ctanh_v4(double xr, double xi, float& tr, float& ti) {
    if (fabs(xr) > 20.0) {
        tr = (float)copysign(1.0, xr);
        ti = 0.0f;
    } else {
        double sh = sinh(2.0 * xr), ch = cosh(2.0 * xr);
        double sn = sin(2.0 * xi),  cs = cos(2.0 * xi);
        double den = ch + cs;
        tr = (float)(sh / den);
        ti = (float)(sn / den);
    }
}

// ---------------------------------------------------------------------------
// fp64 basis tables: c[t*M+m] = cos(2*pi*k_m*t/T), s[t*M+m] = sin(...)
// ---------------------------------------------------------------------------
__global__ void basis_v4(const int* __restrict__ idx,
                         double* __restrict__ c, double* __restrict__ s) {
    int gid = blockIdx.x * 256 + threadIdx.x;
    int t = gid >> 8;                    // M == 256
    int m = gid & (M - 1);
    int k = idx[m];
    int ph = (k * t) & (T - 1);          // exact: k*t < 2^23
    double th = (double)ph * (6.283185307179586476925287 / (double)T);
    c[gid] = cos(th);
    s[gid] = sin(th);
}

// ---------------------------------------------------------------------------
// fp32 TRANSPOSED basis tables for idft: cT[m*T+t] = (float)cos(...),
// identical double->float values as basis_v4's tables. grid (T/256, M).
// ---------------------------------------------------------------------------
__global__ void basisT_v5(const int* __restrict__ idx,
                          float* __restrict__ cT, float* __restrict__ sT) {
    int t = blockIdx.x * 256 + threadIdx.x;
    int m = blockIdx.y;
    int k = idx[m];
    int ph = (k * t) & (T - 1);
    double th = (double)ph * (6.283185307179586476925287 / (double)T);
    cT[(size_t)m * T + t] = (float)cos(th);
    sT[(size_t)m * T + t] = (float)sin(th);
}

// ---------------------------------------------------------------------------
// forward DFT at selected modes — register-tiled fp64 GEMM (unchanged).
// grid (M/64, B*H), block 256
// ---------------------------------------------------------------------------
__launch_bounds__(256)
__global__ void dft_v5(const float* __restrict__ x,
                       const double* __restrict__ bc, const double* __restrict__ bs,
                       float* __restrict__ Xre, float* __restrict__ Xim) {
    __shared__ float  xs[TT][68];
    __shared__ double cs_[TT][66];
    __shared__ double sn_[TT][66];
    int m0 = blockIdx.x * 64;
    int bh = blockIdx.y;
    int b = bh >> 4, h = bh & 15;
    int tid = threadIdx.x;
    int dg = tid & 15, mg = tid >> 4;
    const float* xb = x + (size_t)b * T * H * D + (size_t)h * D;

    double aR[4][4] = {}, aI[4][4] = {};

    for (int t0 = 0; t0 < T; t0 += TT) {
        __syncthreads();
        #pragma unroll
        for (int i = 0; i < 2; i++) {
            int lin = i * 256 + tid;
            int tl = lin >> 4, c4 = lin & 15;
            *(float4*)&xs[tl][c4 * 4] =
                *(const float4*)&xb[(size_t)(t0 + tl) * (H * D) + c4 * 4];
        }
        #pragma unroll
        for (int i = 0; i < 4; i++) {
            int lin = i * 256 + tid;
            int tl = lin >> 5, c2 = lin & 31;
            *(double2*)&cs_[tl][c2 * 2] =
                *(const double2*)&bc[(size_t)(t0 + tl) * M + m0 + c2 * 2];
            *(double2*)&sn_[tl][c2 * 2] =
                *(const double2*)&bs[(size_t)(t0 + tl) * M + m0 + c2 * 2];
        }
        __syncthreads();

        for (int tl = 0; tl < TT; tl++) {
            float4 xf = *(float4*)&xs[tl][dg * 4];
            double xv[4] = {(double)xf.x, (double)xf.y, (double)xf.z, (double)xf.w};
            double2 cA = *(double2*)&cs_[tl][mg * 4];
            double2 cB = *(double2*)&cs_[tl][mg * 4 + 2];
            double2 sA = *(double2*)&sn_[tl][mg * 4];
            double2 sB = *(double2*)&sn_[tl][mg * 4 + 2];
            double cj[4]  = {cA.x, cA.y, cB.x, cB.y};
            double nsj[4] = {-sA.x, -sA.y, -sB.x, -sB.y};
            #pragma unroll
            for (int i2 = 0; i2 < 4; i2++) {
                #pragma unroll
                for (int j = 0; j < 4; j++) {
                    aR[i2][j] = fma(xv[i2], cj[j],  aR[i2][j]);
                    aI[i2][j] = fma(xv[i2], nsj[j], aI[i2][j]);
                }
            }
        }
    }

    #pragma unroll
    for (int i2 = 0; i2 < 4; i2++) {
        int d = dg * 4 + i2;
        size_t base = ((size_t)bh * D + d) * M + m0 + mg * 4;
        #pragma unroll
        for (int j = 0; j < 4; j++) {
            Xre[base + j] = (float)aR[i2][j];
            Xim[base + j] = (float)aI[i2][j];
        }
    }
}

// ---------------------------------------------------------------------------
// fused attn+pv (unchanged). grid (M/32, B*H), block 256.
// ---------------------------------------------------------------------------
__launch_bounds__(256)
__global__ void attnpv_v4(const float* __restrict__ Xq_re, const float* __restrict__ Xq_im,
                          const float* __restrict__ Xk_re, const float* __restrict__ Xk_im,
                          const float* __restrict__ Xv_re, const float* __restrict__ Xv_im,
                          float* __restrict__ xq_re, float* __restrict__ xq_im) {
    __shared__ float qr[64][33], qi[64][33];
    __shared__ float kr[64][33], ki[64][33];
    __shared__ float vr[64][33], vi[64][33];
    __shared__ float atr[32][33], ati[32][33];
    int x0 = blockIdx.x * 32;
    int bh = blockIdx.y;
    int tid = threadIdx.x;
    size_t base = (size_t)bh * D * M;

    #pragma unroll
    for (int i = 0; i < 8; i++) {
        int lin = i * 256 + tid;
        int dd = lin >> 5, xl = lin & 31;
        qr[dd][xl] = Xq_re[base + (size_t)dd * M + x0 + xl];
        qi[dd][xl] = Xq_im[base + (size_t)dd * M + x0 + xl];
    }

    int xa = tid & 31, yga = tid >> 5;
    int dp = tid & 63, xgp = tid >> 6;
    float pr[8] = {0}, pi[8] = {0};

    for (int y0 = 0; y0 < M; y0 += 32) {
        __syncthreads();
        #pragma unroll
        for (int i = 0; i < 8; i++) {
            int lin = i * 256 + tid;
            int dd = lin >> 5, yl = lin & 31;
            size_t g = base + (size_t)dd * M + y0 + yl;
            kr[dd][yl] = Xk_re[g];
            ki[dd][yl] = Xk_im[g];
            vr[dd][yl] = Xv_re[g];
            vi[dd][yl] = Xv_im[g];
        }
        __syncthreads();

        float ar[4] = {0, 0, 0, 0}, ai[4] = {0, 0, 0, 0};
        for (int dd = 0; dd < 64; dd++) {
            float qre = qr[dd][xa], qim = qi[dd][xa];
            #pragma unroll
            for (int jj = 0; jj < 4; jj++) {
                int yl = yga * 4 + jj;
                float kre = kr[dd][yl], kim = ki[dd][yl];
                ar[jj] = fmaf(qre, kre, fmaf(-qim, kim, ar[jj]));
                ai[jj] = fmaf(qre, kim, fmaf(qim, kre, ai[jj]));
            }
        }
        #pragma unroll
        for (int jj = 0; jj < 4; jj++) {
            float tr, ti;
            ctanh_v4((double)ar[jj], (double)ai[jj], tr, ti);
            atr[xa][yga * 4 + jj] = tr;
            ati[xa][yga * 4 + jj] = ti;
        }
        __syncthreads();

        for (int yl = 0; yl < 32; yl++) {
            float vre = vr[dp][yl], vim = vi[dp][yl];
            #pragma unroll
            for (int j = 0; j < 8; j++) {
                int xl = xgp * 8 + j;
                float are = atr[xl][yl], aim = ati[xl][yl];
                pr[j] += are * vre - aim * vim;
                pi[j] += are * vim + aim * vre;
            }
        }
    }
    size_t ob = base + (size_t)dp * M + x0 + xgp * 8;
    #pragma unroll
    for (int j = 0; j < 8; j++) {
        xq_re[ob + j] = pr[j];
        xq_im[ob + j] = pi[j];
    }
}

// ---------------------------------------------------------------------------
// wmul_v5: xw2[bh][m][o] = wsc_m * sum_d xqkv[bh,d,m] * w[h,d,o,m]
// (fp64 accumulation; wsc = (k==0?1:2)*2^-68 folded here — exact pow2,
//  commutes with the fp32 cast -> bit-identical to v4's idft-side scaling).
// Transposed [m][o] store via LDS for coalescing. grid (M/32, B*H).
// ---------------------------------------------------------------------------
__launch_bounds__(256)
__global__ void wmul_v5(const float* __restrict__ xqkv_re, const float* __restrict__ xqkv_im,
                        const float* __restrict__ w_re, const float* __restrict__ w_im,
                        const int* __restrict__ idxq,
                        float* __restrict__ xw2_re, float* __restrict__ xw2_im) {
    __shared__ float xr[64][33], xi[64][33];   // [d][m_local]
    __shared__ float trb[32][68];              // transpose buffer
    int x0 = blockIdx.x * 32;
    int bh = blockIdx.y;
    int h = bh & 15;
    int tid = threadIdx.x;
    int xl = tid & 31, og = tid >> 5;          // og 0..7 -> o = og*8..+7
    size_t base = (size_t)bh * D * M;

    #pragma unroll
    for (int i = 0; i < 8; i++) {
        int lin = i * 256 + tid;
        int dd = lin >> 5, xx = lin & 31;
        xr[dd][xx] = xqkv_re[base + (size_t)dd * M + x0 + xx];
        xi[dd][xx] = xqkv_im[base + (size_t)dd * M + x0 + xx];
    }
    __syncthreads();

    double aR[8] = {0}, aI[8] = {0};
    const float* wrb = w_re + (size_t)h * D * D * M + x0 + xl;
    const float* wib = w_im + (size_t)h * D * D * M + x0 + xl;
    for (int dd = 0; dd < 64; dd++) {
        double xre = (double)xr[dd][xl], xim = (double)xi[dd][xl];
        #pragma unroll
        for (int j = 0; j < 8; j++) {
            int o = og * 8 + j;
            double wre = (double)wrb[((size_t)dd * D + o) * M];
            double wim = (double)wib[((size_t)dd * D + o) * M];
            aR[j] = fma(xre, wre, aR[j]);
            aR[j] = fma(-xim, wim, aR[j]);
            aI[j] = fma(xre, wim, aI[j]);
            aI[j] = fma(xim, wre, aI[j]);
        }
    }

    float wsc = (idxq[x0 + xl] == 0 ? 1.0f : 2.0f) * TOTAL_SCALE;
    size_t obase = (size_t)bh * (M * D) + (size_t)x0 * D;

    // real part: transpose (o,m)->(m,o) then coalesced store
    #pragma unroll
    for (int j = 0; j < 8; j++) trb[xl][og * 8 + j] = (float)aR[j] * wsc;
    __syncthreads();
    #pragma unroll
    for (int i = 0; i < 8; i++) {
        int lin = i * 256 + tid;
        int o = lin & 63, mr = lin >> 6;
        xw2_re[obase + (size_t)mr * D + o] = trb[mr][o];
    }
    __syncthreads();
    // imag part
    #pragma unroll
    for (int j = 0; j < 8; j++) trb[xl][og * 8 + j] = (float)aI[j] * wsc;
    __syncthreads();
    #pragma unroll
    for (int i = 0; i < 8; i++) {
        int lin = i * 256 + tid;
        int o = lin & 63, mr = lin >> 6;
        xw2_im[obase + (size_t)mr * D + o] = trb[mr][o];
    }
}

// ---------------------------------------------------------------------------
// idft_v5: out[b,t,h,o] = sum_m (xw2*cT - xw2_im*sT)  — register-tiled.
// Block: 64 t x 128 cols (2 bh x 64 o); thread (ol, tg2): 16 t x 2 bh.
// Per ml: 8 broadcast float4 (c/s) + 4 conflict-free scalar (w) per 64 FMA.
// Accumulation order identical to idft_v4 (m ascending, c then s term).
// grid (T/64, B*H/2), block 256.
// ---------------------------------------------------------------------------
__launch_bounds__(256)
__global__ void idft_v5(const float* __restrict__ xw2_re, const float* __restrict__ xw2_im,
                        const float* __restrict__ cT, const float* __restrict__ sT,
                        float* __restrict__ out) {
    __shared__ float cc[32][68], ss[32][68];     // [ml][tl]
    __shared__ float wr[32][132], wi[32][132];   // [ml][col]  col = bhl*64+o
    int t0 = blockIdx.x * 64;
    int bh0 = blockIdx.y * 2;
    int tid = threadIdx.x;
    int ol = tid & 63, tg2 = tid >> 6;
    float acc[16][2] = {};

    for (int m0 = 0; m0 < M; m0 += 32) {
        __syncthreads();
        #pragma unroll
        for (int i = 0; i < 2; i++) {            // c/s: 512 float4 each
            int lin = i * 256 + tid;
            int t4 = lin & 15, ml = lin >> 4;
            *(float4*)&cc[ml][t4 * 4] =
                *(const float4*)&cT[(size_t)(m0 + ml) * T + t0 + t4 * 4];
            *(float4*)&ss[ml][t4 * 4] =
                *(const float4*)&sT[(size_t)(m0 + ml) * T + t0 + t4 * 4];
        }
        #pragma unroll
        for (int i = 0; i < 4; i++) {            // w: 1024 float4 each
            int lin = i * 256 + tid;
            int o4 = lin & 15, ml = (lin >> 4) & 31, bhl = lin >> 9;
            size_t g = (size_t)(bh0 + bhl) * (M * D) + (size_t)(m0 + ml) * D + o4 * 4;
            *(float4*)&wr[ml][bhl * 64 + o4 * 4] = *(const float4*)&xw2_re[g];
            *(float4*)&wi[ml][bhl * 64 + o4 * 4] = *(const float4*)&xw2_im[g];
        }
        __syncthreads();

        for (int ml = 0; ml < 32; ml++) {
            float4 c4[4], s4[4];
            #pragma unroll
            for (int k = 0; k < 4; k++) {
                c4[k] = *(float4*)&cc[ml][tg2 * 16 + k * 4];
                s4[k] = *(float4*)&ss[ml][tg2 * 16 + k * 4];
            }
            float w0r = wr[ml][ol],      w0i = wi[ml][ol];
            float w1r = wr[ml][64 + ol], w1i = wi[ml][64 + ol];
            #pragma unroll
            for (int k = 0; k < 4; k++) {
                float cv[4] = {c4[k].x, c4[k].y, c4[k].z, c4[k].w};
                float sv[4] = {s4[k].x, s4[k].y, s4[k].z, s4[k].w};
                #pragma unroll
                for (int e = 0; e < 4; e++) {
                    int i = k * 4 + e;
                    acc[i][0] = fmaf(cv[e], w0r, acc[i][0]);
                    acc[i][0] = fmaf(-sv[e], w0i, acc[i][0]);
                    acc[i][1] = fmaf(cv[e], w1r, acc[i][1]);
                    acc[i][1] = fmaf(-sv[e], w1i, acc[i][1]);
                }
            }
        }
    }

    #pragma unroll
    for (int bhl = 0; bhl < 2; bhl++) {
        int bh = bh0 + bhl;
        int b = bh >> 4, h = bh & 15;
        #pragma unroll
        for (int i = 0; i < 16; i++) {
            int t = t0 + tg2 * 16 + i;
            out[(((size_t)b * T + t) * H + h) * D + ol] = acc[i][bhl];
        }
    }
}

// ---------------------------------------------------------------------------
extern "C" void kernel_launch(void* const* d_in, const int* in_sizes, int n_in,
                              void* d_out, int out_size, void* d_ws, size_t ws_size,
                              hipStream_t stream) {
    const float* q    = (const float*)d_in[0];
    const float* k    = (const float*)d_in[1];
    const float* v    = (const float*)d_in[2];
    const float* w_re = (const float*)d_in[3];
    const float* w_im = (const float*)d_in[4];
    const int* idx_q  = (const int*)d_in[5];
    const int* idx_kv = (const int*)d_in[6];
    float* out = (float*)d_out;

    const size_t TM  = (size_t)T * M;          // 1,048,576
    const size_t XSZ = (size_t)B * H * D * M;  // 2,097,152

    // ---- ws: 32 MiB fp64 basis + 48 MiB fp32 X/xw + 8 MiB fp32 T-basis = 88 MiB
    double* bq_c  = (double*)d_ws;             // fp64 basis (index_q)
    double* bq_s  = bq_c + TM;
    double* bkv_c = bq_s + TM;                 // fp64 basis (index_kv)
    double* bkv_s = bkv_c + TM;
    float*  Xv_re = (float*)(bkv_s + TM);
    float*  Xv_im = Xv_re + XSZ;
    float*  xqkv_re = Xv_im + XSZ;
    float*  xqkv_im = xqkv_re + XSZ;
    float*  xw2_re = xqkv_im + XSZ;
    float*  xw2_im = xw2_re + XSZ;
    float*  cTf = xw2_im + XSZ;                // fp32 [m][T] basis (index_q)
    float*  sTf = cTf + TM;

    // ---- d_out scratch: Xq/Xk fp32 (33.5 MB at the tail); consumed by
    //      attnpv before idft_v5 rewrites every element of d_out. ------
    float* Xq_re32 = out + (size_t)out_size - 4 * XSZ;
    float* Xq_im32 = Xq_re32 + XSZ;
    float* Xk_re32 = Xq_im32 + XSZ;
    float* Xk_im32 = Xk_re32 + XSZ;

    basis_v4<<<TM / 256, 256, 0, stream>>>(idx_q, bq_c, bq_s);
    basis_v4<<<TM / 256, 256, 0, stream>>>(idx_kv, bkv_c, bkv_s);
    basisT_v5<<<dim3(T / 256, M), 256, 0, stream>>>(idx_q, cTf, sTf);

    dft_v5<<<dim3(M / 64, B * H), 256, 0, stream>>>(q, bq_c, bq_s, Xq_re32, Xq_im32);
    dft_v5<<<dim3(M / 64, B * H), 256, 0, stream>>>(k, bkv_c, bkv_s, Xk_re32, Xk_im32);
    dft_v5<<<dim3(M / 64, B * H), 256, 0, stream>>>(v, bkv_c, bkv_s, Xv_re, Xv_im);

    attnpv_v4<<<dim3(M / 32, B * H), 256, 0, stream>>>(
        Xq_re32, Xq_im32, Xk_re32, Xk_im32, Xv_re, Xv_im, xqkv_re, xqkv_im);

    wmul_v5<<<dim3(M / 32, B * H), 256, 0, stream>>>(
        xqkv_re, xqkv_im, w_re, w_im, idx_q, xw2_re, xw2_im);

    idft_v5<<<dim3(T / 64, B * H / 2), 256, 0, stream>>>(
        xw2_re, xw2_im, cTf, sTf, out);
}

// Round 12
// 3226.612 us; speedup vs baseline: 2.1608x; 1.1109x over previous
//
#include <hip/hip_runtime.h>
#include <math.h>

#define B 8
#define T 4096
#define H 16
#define D 64
#define M 256
#define TT 32   // DFT t-tile

// SCALE = 2^-28 applied twice; irfft 1/T = 2^-12  ->  2^-68 (exact pow2)
#define TOTAL_SCALE 3.3881317890172014e-21f

// ---------------------------------------------------------------------------
// stable complex tanh, fp64 in, fp32 out
// ---------------------------------------------------------------------------
__device__ inline void ctanh_v4(double xr, double xi, float& tr, float& ti) {
    if (fabs(xr) > 20.0) {
        tr = (float)copysign(1.0, xr);
        ti = 0.0f;
    } else {
        double sh = sinh(2.0 * xr), ch = cosh(2.0 * xr);
        double sn = sin(2.0 * xi),  cs = cos(2.0 * xi);
        double den = ch + cs;
        tr = (float)(sh / den);
        ti = (float)(sn / den);
    }
}

// ---------------------------------------------------------------------------
// fp64 basis tables: c[t*M+m] = cos(2*pi*k_m*t/T), s[t*M+m] = sin(...)
// ---------------------------------------------------------------------------
__global__ void basis_v4(const int* __restrict__ idx,
                         double* __restrict__ c, double* __restrict__ s) {
    int gid = blockIdx.x * 256 + threadIdx.x;
    int t = gid >> 8;                    // M == 256
    int m = gid & (M - 1);
    int k = idx[m];
    int ph = (k * t) & (T - 1);          // exact: k*t < 2^23
    double th = (double)ph * (6.283185307179586476925287 / (double)T);
    c[gid] = cos(th);
    s[gid] = sin(th);
}

// ---------------------------------------------------------------------------
// fp32 TRANSPOSED basis tables for idft: cT[m*T+t] = (float)cos(...),
// identical double->float values as basis_v4's tables. grid (T/256, M).
// ---------------------------------------------------------------------------
__global__ void basisT_v5(const int* __restrict__ idx,
                          float* __restrict__ cT, float* __restrict__ sT) {
    int t = blockIdx.x * 256 + threadIdx.x;
    int m = blockIdx.y;
    int k = idx[m];
    int ph = (k * t) & (T - 1);
    double th = (double)ph * (6.283185307179586476925287 / (double)T);
    cT[(size_t)m * T + t] = (float)cos(th);
    sT[(size_t)m * T + t] = (float)sin(th);
}

// ---------------------------------------------------------------------------
// forward DFT (fp64, bit-exact path) — register-tiled fp64 GEMM.
// Used for Q. grid (M/64, B*H), block 256
// ---------------------------------------------------------------------------
__launch_bounds__(256)
__global__ void dft_v5(const float* __restrict__ x,
                       const double* __restrict__ bc, const double* __restrict__ bs,
                       float* __restrict__ Xre, float* __restrict__ Xim) {
    __shared__ float  xs[TT][68];
    __shared__ double cs_[TT][66];
    __shared__ double sn_[TT][66];
    int m0 = blockIdx.x * 64;
    int bh = blockIdx.y;
    int b = bh >> 4, h = bh & 15;
    int tid = threadIdx.x;
    int dg = tid & 15, mg = tid >> 4;
    const float* xb = x + (size_t)b * T * H * D + (size_t)h * D;

    double aR[4][4] = {}, aI[4][4] = {};

    for (int t0 = 0; t0 < T; t0 += TT) {
        __syncthreads();
        #pragma unroll
        for (int i = 0; i < 2; i++) {
            int lin = i * 256 + tid;
            int tl = lin >> 4, c4 = lin & 15;
            *(float4*)&xs[tl][c4 * 4] =
                *(const float4*)&xb[(size_t)(t0 + tl) * (H * D) + c4 * 4];
        }
        #pragma unroll
        for (int i = 0; i < 4; i++) {
            int lin = i * 256 + tid;
            int tl = lin >> 5, c2 = lin & 31;
            *(double2*)&cs_[tl][c2 * 2] =
                *(const double2*)&bc[(size_t)(t0 + tl) * M + m0 + c2 * 2];
            *(double2*)&sn_[tl][c2 * 2] =
                *(const double2*)&bs[(size_t)(t0 + tl) * M + m0 + c2 * 2];
        }
        __syncthreads();

        for (int tl = 0; tl < TT; tl++) {
            float4 xf = *(float4*)&xs[tl][dg * 4];
            double xv[4] = {(double)xf.x, (double)xf.y, (double)xf.z, (double)xf.w};
            double2 cA = *(double2*)&cs_[tl][mg * 4];
            double2 cB = *(double2*)&cs_[tl][mg * 4 + 2];
            double2 sA = *(double2*)&sn_[tl][mg * 4];
            double2 sB = *(double2*)&sn_[tl][mg * 4 + 2];
            double cj[4]  = {cA.x, cA.y, cB.x, cB.y};
            double nsj[4] = {-sA.x, -sA.y, -sB.x, -sB.y};
            #pragma unroll
            for (int i2 = 0; i2 < 4; i2++) {
                #pragma unroll
                for (int j = 0; j < 4; j++) {
                    aR[i2][j] = fma(xv[i2], cj[j],  aR[i2][j]);
                    aI[i2][j] = fma(xv[i2], nsj[j], aI[i2][j]);
                }
            }
        }
    }

    #pragma unroll
    for (int i2 = 0; i2 < 4; i2++) {
        int d = dg * 4 + i2;
        size_t base = ((size_t)bh * D + d) * M + m0 + mg * 4;
        #pragma unroll
        for (int j = 0; j < 4; j++) {
            Xre[base + j] = (float)aR[i2][j];
            Xim[base + j] = (float)aI[i2][j];
        }
    }
}

// ---------------------------------------------------------------------------
// FUSED K+V DFT sharing one basis tile (index_kv).
//   K: fp64 FMA, accumulation sequence IDENTICAL to dft_v5 -> bit-identical Xk.
//   V: fp32 FMA (linear path; error budget ~1e-6 rel -> ~1e-19 at output).
// grid (M/64, B*H), block 256
// ---------------------------------------------------------------------------
__launch_bounds__(256)
__global__ void dft_kv_v6(const float* __restrict__ xk, const float* __restrict__ xv,
                          const double* __restrict__ bc, const double* __restrict__ bs,
                          float* __restrict__ Kre, float* __restrict__ Kim,
                          float* __restrict__ Vre, float* __restrict__ Vim) {
    __shared__ float  xks[TT][68];
    __shared__ float  xvs[TT][68];
    __shared__ double cs_[TT][66];
    __shared__ double sn_[TT][66];
    int m0 = blockIdx.x * 64;
    int bh = blockIdx.y;
    int b = bh >> 4, h = bh & 15;
    int tid = threadIdx.x;
    int dg = tid & 15, mg = tid >> 4;
    const float* xkb = xk + (size_t)b * T * H * D + (size_t)h * D;
    const float* xvb = xv + (size_t)b * T * H * D + (size_t)h * D;

    double kR[4][4] = {}, kI[4][4] = {};
    float  vR[4][4] = {}, vI[4][4] = {};

    for (int t0 = 0; t0 < T; t0 += TT) {
        __syncthreads();
        #pragma unroll
        for (int i = 0; i < 2; i++) {
            int lin = i * 256 + tid;
            int tl = lin >> 4, c4 = lin & 15;
            size_t g = (size_t)(t0 + tl) * (H * D) + c4 * 4;
            *(float4*)&xks[tl][c4 * 4] = *(const float4*)&xkb[g];
            *(float4*)&xvs[tl][c4 * 4] = *(const float4*)&xvb[g];
        }
        #pragma unroll
        for (int i = 0; i < 4; i++) {
            int lin = i * 256 + tid;
            int tl = lin >> 5, c2 = lin & 31;
            *(double2*)&cs_[tl][c2 * 2] =
                *(const double2*)&bc[(size_t)(t0 + tl) * M + m0 + c2 * 2];
            *(double2*)&sn_[tl][c2 * 2] =
                *(const double2*)&bs[(size_t)(t0 + tl) * M + m0 + c2 * 2];
        }
        __syncthreads();

        for (int tl = 0; tl < TT; tl++) {
            float4 xkf = *(float4*)&xks[tl][dg * 4];
            float4 xvf = *(float4*)&xvs[tl][dg * 4];
            double xkv[4] = {(double)xkf.x, (double)xkf.y, (double)xkf.z, (double)xkf.w};
            float  xvv[4] = {xvf.x, xvf.y, xvf.z, xvf.w};
            double2 cA = *(double2*)&cs_[tl][mg * 4];
            double2 cB = *(double2*)&cs_[tl][mg * 4 + 2];
            double2 sA = *(double2*)&sn_[tl][mg * 4];
            double2 sB = *(double2*)&sn_[tl][mg * 4 + 2];
            double cj[4]  = {cA.x, cA.y, cB.x, cB.y};
            double nsj[4] = {-sA.x, -sA.y, -sB.x, -sB.y};
            float  cjf[4]  = {(float)cA.x, (float)cA.y, (float)cB.x, (float)cB.y};
            float  nsjf[4] = {(float)-sA.x, (float)-sA.y, (float)-sB.x, (float)-sB.y};
            #pragma unroll
            for (int i2 = 0; i2 < 4; i2++) {
                #pragma unroll
                for (int j = 0; j < 4; j++) {
                    kR[i2][j] = fma(xkv[i2], cj[j],  kR[i2][j]);
                    kI[i2][j] = fma(xkv[i2], nsj[j], kI[i2][j]);
                    vR[i2][j] = fmaf(xvv[i2], cjf[j],  vR[i2][j]);
                    vI[i2][j] = fmaf(xvv[i2], nsjf[j], vI[i2][j]);
                }
            }
        }
    }

    #pragma unroll
    for (int i2 = 0; i2 < 4; i2++) {
        int d = dg * 4 + i2;
        size_t base = ((size_t)bh * D + d) * M + m0 + mg * 4;
        #pragma unroll
        for (int j = 0; j < 4; j++) {
            Kre[base + j] = (float)kR[i2][j];
            Kim[base + j] = (float)kI[i2][j];
            Vre[base + j] = vR[i2][j];
            Vim[base + j] = vI[i2][j];
        }
    }
}

// ---------------------------------------------------------------------------
// fused attn+pv (unchanged). grid (M/32, B*H), block 256.
// ---------------------------------------------------------------------------
__launch_bounds__(256)
__global__ void attnpv_v4(const float* __restrict__ Xq_re, const float* __restrict__ Xq_im,
                          const float* __restrict__ Xk_re, const float* __restrict__ Xk_im,
                          const float* __restrict__ Xv_re, const float* __restrict__ Xv_im,
                          float* __restrict__ xq_re, float* __restrict__ xq_im) {
    __shared__ float qr[64][33], qi[64][33];
    __shared__ float kr[64][33], ki[64][33];
    __shared__ float vr[64][33], vi[64][33];
    __shared__ float atr[32][33], ati[32][33];
    int x0 = blockIdx.x * 32;
    int bh = blockIdx.y;
    int tid = threadIdx.x;
    size_t base = (size_t)bh * D * M;

    #pragma unroll
    for (int i = 0; i < 8; i++) {
        int lin = i * 256 + tid;
        int dd = lin >> 5, xl = lin & 31;
        qr[dd][xl] = Xq_re[base + (size_t)dd * M + x0 + xl];
        qi[dd][xl] = Xq_im[base + (size_t)dd * M + x0 + xl];
    }

    int xa = tid & 31, yga = tid >> 5;
    int dp = tid & 63, xgp = tid >> 6;
    float pr[8] = {0}, pi[8] = {0};

    for (int y0 = 0; y0 < M; y0 += 32) {
        __syncthreads();
        #pragma unroll
        for (int i = 0; i < 8; i++) {
            int lin = i * 256 + tid;
            int dd = lin >> 5, yl = lin & 31;
            size_t g = base + (size_t)dd * M + y0 + yl;
            kr[dd][yl] = Xk_re[g];
            ki[dd][yl] = Xk_im[g];
            vr[dd][yl] = Xv_re[g];
            vi[dd][yl] = Xv_im[g];
        }
        __syncthreads();

        float ar[4] = {0, 0, 0, 0}, ai[4] = {0, 0, 0, 0};
        for (int dd = 0; dd < 64; dd++) {
            float qre = qr[dd][xa], qim = qi[dd][xa];
            #pragma unroll
            for (int jj = 0; jj < 4; jj++) {
                int yl = yga * 4 + jj;
                float kre = kr[dd][yl], kim = ki[dd][yl];
                ar[jj] = fmaf(qre, kre, fmaf(-qim, kim, ar[jj]));
                ai[jj] = fmaf(qre, kim, fmaf(qim, kre, ai[jj]));
            }
        }
        #pragma unroll
        for (int jj = 0; jj < 4; jj++) {
            float tr, ti;
            ctanh_v4((double)ar[jj], (double)ai[jj], tr, ti);
            atr[xa][yga * 4 + jj] = tr;
            ati[xa][yga * 4 + jj] = ti;
        }
        __syncthreads();

        for (int yl = 0; yl < 32; yl++) {
            float vre = vr[dp][yl], vim = vi[dp][yl];
            #pragma unroll
            for (int j = 0; j < 8; j++) {
                int xl = xgp * 8 + j;
                float are = atr[xl][yl], aim = ati[xl][yl];
                pr[j] += are * vre - aim * vim;
                pi[j] += are * vim + aim * vre;
            }
        }
    }
    size_t ob = base + (size_t)dp * M + x0 + xgp * 8;
    #pragma unroll
    for (int j = 0; j < 8; j++) {
        xq_re[ob + j] = pr[j];
        xq_im[ob + j] = pi[j];
    }
}

// ---------------------------------------------------------------------------
// wmul_v5 (unchanged): xw2[bh][m][o] = wsc_m * sum_d xqkv[bh,d,m]*w[h,d,o,m]
// grid (M/32, B*H).
// ---------------------------------------------------------------------------
__launch_bounds__(256)
__global__ void wmul_v5(const float* __restrict__ xqkv_re, const float* __restrict__ xqkv_im,
                        const float* __restrict__ w_re, const float* __restrict__ w_im,
                        const int* __restrict__ idxq,
                        float* __restrict__ xw2_re, float* __restrict__ xw2_im) {
    __shared__ float xr[64][33], xi[64][33];
    __shared__ float trb[32][68];
    int x0 = blockIdx.x * 32;
    int bh = blockIdx.y;
    int h = bh & 15;
    int tid = threadIdx.x;
    int xl = tid & 31, og = tid >> 5;
    size_t base = (size_t)bh * D * M;

    #pragma unroll
    for (int i = 0; i < 8; i++) {
        int lin = i * 256 + tid;
        int dd = lin >> 5, xx = lin & 31;
        xr[dd][xx] = xqkv_re[base + (size_t)dd * M + x0 + xx];
        xi[dd][xx] = xqkv_im[base + (size_t)dd * M + x0 + xx];
    }
    __syncthreads();

    double aR[8] = {0}, aI[8] = {0};
    const float* wrb = w_re + (size_t)h * D * D * M + x0 + xl;
    const float* wib = w_im + (size_t)h * D * D * M + x0 + xl;
    for (int dd = 0; dd < 64; dd++) {
        double xre = (double)xr[dd][xl], xim = (double)xi[dd][xl];
        #pragma unroll
        for (int j = 0; j < 8; j++) {
            int o = og * 8 + j;
            double wre = (double)wrb[((size_t)dd * D + o) * M];
            double wim = (double)wib[((size_t)dd * D + o) * M];
            aR[j] = fma(xre, wre, aR[j]);
            aR[j] = fma(-xim, wim, aR[j]);
            aI[j] = fma(xre, wim, aI[j]);
            aI[j] = fma(xim, wre, aI[j]);
        }
    }

    float wsc = (idxq[x0 + xl] == 0 ? 1.0f : 2.0f) * TOTAL_SCALE;
    size_t obase = (size_t)bh * (M * D) + (size_t)x0 * D;

    #pragma unroll
    for (int j = 0; j < 8; j++) trb[xl][og * 8 + j] = (float)aR[j] * wsc;
    __syncthreads();
    #pragma unroll
    for (int i = 0; i < 8; i++) {
        int lin = i * 256 + tid;
        int o = lin & 63, mr = lin >> 6;
        xw2_re[obase + (size_t)mr * D + o] = trb[mr][o];
    }
    __syncthreads();
    #pragma unroll
    for (int j = 0; j < 8; j++) trb[xl][og * 8 + j] = (float)aI[j] * wsc;
    __syncthreads();
    #pragma unroll
    for (int i = 0; i < 8; i++) {
        int lin = i * 256 + tid;
        int o = lin & 63, mr = lin >> 6;
        xw2_im[obase + (size_t)mr * D + o] = trb[mr][o];
    }
}

// ---------------------------------------------------------------------------
// idft_v5 (unchanged). grid (T/64, B*H/2), block 256.
// ---------------------------------------------------------------------------
__launch_bounds__(256)
__global__ void idft_v5(const float* __restrict__ xw2_re, const float* __restrict__ xw2_im,
                        const float* __restrict__ cT, const float* __restrict__ sT,
                        float* __restrict__ out) {
    __shared__ float cc[32][68], ss[32][68];
    __shared__ float wr[32][132], wi[32][132];
    int t0 = blockIdx.x * 64;
    int bh0 = blockIdx.y * 2;
    int tid = threadIdx.x;
    int ol = tid & 63, tg2 = tid >> 6;
    float acc[16][2] = {};

    for (int m0 = 0; m0 < M; m0 += 32) {
        __syncthreads();
        #pragma unroll
        for (int i = 0; i < 2; i++) {
            int lin = i * 256 + tid;
            int t4 = lin & 15, ml = lin >> 4;
            *(float4*)&cc[ml][t4 * 4] =
                *(const float4*)&cT[(size_t)(m0 + ml) * T + t0 + t4 * 4];
            *(float4*)&ss[ml][t4 * 4] =
                *(const float4*)&sT[(size_t)(m0 + ml) * T + t0 + t4 * 4];
        }
        #pragma unroll
        for (int i = 0; i < 4; i++) {
            int lin = i * 256 + tid;
            int o4 = lin & 15, ml = (lin >> 4) & 31, bhl = lin >> 9;
            size_t g = (size_t)(bh0 + bhl) * (M * D) + (size_t)(m0 + ml) * D + o4 * 4;
            *(float4*)&wr[ml][bhl * 64 + o4 * 4] = *(const float4*)&xw2_re[g];
            *(float4*)&wi[ml][bhl * 64 + o4 * 4] = *(const float4*)&xw2_im[g];
        }
        __syncthreads();

        for (int ml = 0; ml < 32; ml++) {
            float4 c4[4], s4[4];
            #pragma unroll
            for (int k = 0; k < 4; k++) {
                c4[k] = *(float4*)&cc[ml][tg2 * 16 + k * 4];
                s4[k] = *(float4*)&ss[ml][tg2 * 16 + k * 4];
            }
            float w0r = wr[ml][ol],      w0i = wi[ml][ol];
            float w1r = wr[ml][64 + ol], w1i = wi[ml][64 + ol];
            #pragma unroll
            for (int k = 0; k < 4; k++) {
                float cv[4] = {c4[k].x, c4[k].y, c4[k].z, c4[k].w};
                float sv[4] = {s4[k].x, s4[k].y, s4[k].z, s4[k].w};
                #pragma unroll
                for (int e = 0; e < 4; e++) {
                    int i = k * 4 + e;
                    acc[i][0] = fmaf(cv[e], w0r, acc[i][0]);
                    acc[i][0] = fmaf(-sv[e], w0i, acc[i][0]);
                    acc[i][1] = fmaf(cv[e], w1r, acc[i][1]);
                    acc[i][1] = fmaf(-sv[e], w1i, acc[i][1]);
                }
            }
        }
    }

    #pragma unroll
    for (int bhl = 0; bhl < 2; bhl++) {
        int bh = bh0 + bhl;
        int b = bh >> 4, h = bh & 15;
        #pragma unroll
        for (int i = 0; i < 16; i++) {
            int t = t0 + tg2 * 16 + i;
            out[(((size_t)b * T + t) * H + h) * D + ol] = acc[i][bhl];
        }
    }
}

// ---------------------------------------------------------------------------
extern "C" void kernel_launch(void* const* d_in, const int* in_sizes, int n_in,
                              void* d_out, int out_size, void* d_ws, size_t ws_size,
                              hipStream_t stream) {
    const float* q    = (const float*)d_in[0];
    const float* k    = (const float*)d_in[1];
    const float* v    = (const float*)d_in[2];
    const float* w_re = (const float*)d_in[3];
    const float* w_im = (const float*)d_in[4];
    const int* idx_q  = (const int*)d_in[5];
    const int* idx_kv = (const int*)d_in[6];
    float* out = (float*)d_out;

    const size_t TM  = (size_t)T * M;          // 1,048,576
    const size_t XSZ = (size_t)B * H * D * M;  // 2,097,152

    // ---- ws: 32 MiB fp64 basis + 48 MiB fp32 X/xw + 8 MiB fp32 T-basis = 88 MiB
    double* bq_c  = (double*)d_ws;
    double* bq_s  = bq_c + TM;
    double* bkv_c = bq_s + TM;
    double* bkv_s = bkv_c + TM;
    float*  Xv_re = (float*)(bkv_s + TM);
    float*  Xv_im = Xv_re + XSZ;
    float*  xqkv_re = Xv_im + XSZ;
    float*  xqkv_im = xqkv_re + XSZ;
    float*  xw2_re = xqkv_im + XSZ;
    float*  xw2_im = xw2_re + XSZ;
    float*  cTf = xw2_im + XSZ;
    float*  sTf = cTf + TM;

    // ---- d_out scratch: Xq/Xk fp32 at the tail; consumed by attnpv before
    //      idft_v5 rewrites every element of d_out. ----
    float* Xq_re32 = out + (size_t)out_size - 4 * XSZ;
    float* Xq_im32 = Xq_re32 + XSZ;
    float* Xk_re32 = Xq_im32 + XSZ;
    float* Xk_im32 = Xk_re32 + XSZ;

    basis_v4<<<TM / 256, 256, 0, stream>>>(idx_q, bq_c, bq_s);
    basis_v4<<<TM / 256, 256, 0, stream>>>(idx_kv, bkv_c, bkv_s);
    basisT_v5<<<dim3(T / 256, M), 256, 0, stream>>>(idx_q, cTf, sTf);

    dft_v5<<<dim3(M / 64, B * H), 256, 0, stream>>>(q, bq_c, bq_s, Xq_re32, Xq_im32);
    dft_kv_v6<<<dim3(M / 64, B * H), 256, 0, stream>>>(
        k, v, bkv_c, bkv_s, Xk_re32, Xk_im32, Xv_re, Xv_im);

    attnpv_v4<<<dim3(M / 32, B * H), 256, 0, stream>>>(
        Xq_re32, Xq_im32, Xk_re32, Xk_im32, Xv_re, Xv_im, xqkv_re, xqkv_im);

    wmul_v5<<<dim3(M / 32, B * H), 256, 0, stream>>>(
        xqkv_re, xqkv_im, w_re, w_im, idx_q, xw2_re, xw2_im);

    idft_v5<<<dim3(T / 64, B * H / 2), 256, 0, stream>>>(
        xw2_re, xw2_im, cTf, sTf, out);
}